// Round 14
// baseline (248.228 us; speedup 1.0000x reference)
//
#include <hip/hip_runtime.h>

typedef unsigned short u16;
typedef unsigned int   u32;

#define Bv  16
#define Nv  512
#define Cv  512
#define NSv 16
#define CCv 64

typedef __attribute__((ext_vector_type(8))) short bf16x8;
typedef __attribute__((ext_vector_type(4))) float f32x4;

__device__ __forceinline__ u16 f2bf(float f) {   // RNE fp32 -> bf16
  u32 b = __float_as_uint(f);
  return (u16)((b + 0x7fffu + ((b >> 16) & 1u)) >> 16);
}
__device__ __forceinline__ u32 pack2(float lo, float hi) {
  return (u32)f2bf(lo) | ((u32)f2bf(hi) << 16);
}
__device__ __forceinline__ u32 cvtpk(float lo, float hi) {  // 1-instr RNE pack (T12 recipe)
  u32 r;
  asm("v_cvt_pk_bf16_f32 %0, %1, %2" : "=v"(r) : "v"(lo), "v"(hi));
  return r;
}
__device__ __forceinline__ float bfl(u32 w) { return __uint_as_float(w << 16); }
__device__ __forceinline__ float bfh(u32 w) { return __uint_as_float(w & 0xffff0000u); }

// global -> LDS direct (16B/lane); LDS dest must be wave-uniform base, lane i lands at +16*i
#define GLD_LDS16(gp, lp)                                                              \
  __builtin_amdgcn_global_load_lds(                                                    \
      (const __attribute__((address_space(1))) u32*)(const void*)(gp),                 \
      (__attribute__((address_space(3))) u32*)(lp), 16, 0, 0)

// ---------------- prep: knn (blocks 0..255, full-chip) + cvt (blocks 256..1535) ----------
// knn: 8 lanes/query x 64 candidates, reg-resident ripple-16, tournament merge via shfl.
// Output is the top-16 SET (order-free: all downstream NS-axis ops are symmetric).
__global__ __launch_bounds__(256) void prep_kernel(
    const float* __restrict__ p, int* __restrict__ idx_out,
    const float* __restrict__ x,
    const float* __restrict__ Wq, const float* __restrict__ Wk, const float* __restrict__ Wv,
    const float* __restrict__ w1W, const float* __restrict__ w2W,
    u16* __restrict__ xbT, u16* __restrict__ Wcat,
    u16* __restrict__ w1p, u16* __restrict__ w2p) {
  __shared__ __align__(16) char ARB[16640];   // knn: pnts 8 KB; cvt: lt 16.6 KB
  const int t = threadIdx.x;
  if (blockIdx.x < 256) {
#pragma clang fp contract(off)
    float4* pnts = (float4*)ARB;
    const int b  = blockIdx.x >> 4;
    const int q0 = (blockIdx.x & 15) * 32;
    for (int e = t; e < Nv; e += 256) {
      float xx = p[(b * Nv + e) * 3 + 0];
      float yy = p[(b * Nv + e) * 3 + 1];
      float zz = p[(b * Nv + e) * 3 + 2];
      float s = ((xx * xx) + (yy * yy)) + (zz * zz);
      pnts[e] = make_float4(xx, yy, zz, s);
    }
    __syncthreads();
    const int q  = q0 + (t >> 3);   // 32 queries/block, 8 lanes each
    const int pt = t & 7;           // candidate part: m in [pt*64, pt*64+64)
    const float4 qp = pnts[q];
    float bd[NSv]; int bi[NSv];
#pragma unroll
    for (int i = 0; i < NSv; i++) { bd[i] = 1e30f; bi[i] = 0; }
    const int m0 = pt * 64;
#pragma unroll 1
    for (int i = 0; i < 64; i++) {
      const int m = m0 + i;
      const float4 c = pnts[m];
      float dot = __builtin_fmaf(qp.z, c.z, __builtin_fmaf(qp.y, c.y, qp.x * c.x));
      float d = (qp.w + c.w) - (2.0f * dot);
      bool cm[NSv];
#pragma unroll
      for (int j = 0; j < NSv; j++) cm[j] = bd[j] > d;
#pragma unroll
      for (int j = NSv - 1; j > 0; j--) {
        bd[j] = cm[j - 1] ? bd[j - 1] : (cm[j] ? d : bd[j]);
        bi[j] = cm[j - 1] ? bi[j - 1] : (cm[j] ? m : bi[j]);
      }
      bd[0] = cm[0] ? d : bd[0];
      bi[0] = cm[0] ? m : bi[0];
    }
    // tournament merge: 16 pops; ties -> lower part (= lower m, matches top_k tie-break)
    int h = 0;
#pragma unroll 1
    for (int s = 0; s < 16; s++) {
      float mv = bd[0]; int ml = pt;
      {
        float ov = __shfl_xor(mv, 1); int ol = __shfl_xor(ml, 1);
        bool tk = (ov < mv) || (ov == mv && ol < ml);
        mv = tk ? ov : mv; ml = tk ? ol : ml;
      }
      {
        float ov = __shfl_xor(mv, 2); int ol = __shfl_xor(ml, 2);
        bool tk = (ov < mv) || (ov == mv && ol < ml);
        mv = tk ? ov : mv; ml = tk ? ol : ml;
      }
      {
        float ov = __shfl_xor(mv, 4); int ol = __shfl_xor(ml, 4);
        bool tk = (ov < mv) || (ov == mv && ol < ml);
        mv = tk ? ov : mv; ml = tk ? ol : ml;
      }
      if (ml == pt) {   // I own the min: pop head (shift value list; bi stays in place)
#pragma unroll
        for (int j = 0; j < 15; j++) bd[j] = bd[j + 1];
        bd[15] = 1e30f;
        h++;
      }
    }
    // exclusive prefix of h over the 8-lane group -> output offset
    const int lane = t & 63, gbase = lane & 56;
    int pre = 0;
#pragma unroll
    for (int j = 0; j < 7; j++) {
      int hj = __shfl(h, gbase + j);
      if (j < pt) pre += hj;
    }
    int* o = idx_out + (b * Nv + q) * NSv + pre;
#pragma unroll
    for (int j = 0; j < 16; j++)
      if (j < h) o[j] = bi[j];
  } else {
    // ---- cvt: fp32 -> bf16 transpose/convert ----
    float (*lt)[65] = (float(*)[65])ARB;
    const int id = blockIdx.x - 256;
    const int tile = id & 63, unit = id >> 6;
    const float* src; u16* dst;
    int k0, c0, srcC, dstC;
    if (unit < 16) {
      src = x + unit * 262144; dst = xbT + unit * 262144;
      k0 = (tile & 7) * 64; c0 = (tile >> 3) * 64; srcC = 512; dstC = 512;
    } else if (unit < 19) {
      const int mat = unit - 16;
      src = (mat == 0) ? Wq : (mat == 1) ? Wk : Wv;
      dst = Wcat + mat * 262144;
      k0 = (tile & 7) * 64; c0 = (tile >> 3) * 64; srcC = 512; dstC = 512;
    } else {
      if (tile < 8)       { src = w1W; dst = w1p; k0 = tile * 64; c0 = 0; srcC = 64; dstC = 512; }
      else if (tile == 8) { src = w2W; dst = w2p; k0 = 0; c0 = 0; srcC = 64; dstC = 64; }
      else return;
    }
    {
      const int r = t >> 2, cq = (t & 3) * 16;
      const float* s = src + (k0 + r) * srcC + c0 + cq;
#pragma unroll
      for (int i = 0; i < 4; i++) {
        const float4 v = *(const float4*)&s[i * 4];
        lt[r][cq + i * 4 + 0] = v.x;
        lt[r][cq + i * 4 + 1] = v.y;
        lt[r][cq + i * 4 + 2] = v.z;
        lt[r][cq + i * 4 + 3] = v.w;
      }
    }
    __syncthreads();
    {
      const int rr = t >> 2, kq = (t & 3) * 16;
      uint4 pa, pb;
      pa.x = pack2(lt[kq + 0][rr],  lt[kq + 1][rr]);
      pa.y = pack2(lt[kq + 2][rr],  lt[kq + 3][rr]);
      pa.z = pack2(lt[kq + 4][rr],  lt[kq + 5][rr]);
      pa.w = pack2(lt[kq + 6][rr],  lt[kq + 7][rr]);
      pb.x = pack2(lt[kq + 8][rr],  lt[kq + 9][rr]);
      pb.y = pack2(lt[kq + 10][rr], lt[kq + 11][rr]);
      pb.z = pack2(lt[kq + 12][rr], lt[kq + 13][rr]);
      pb.w = pack2(lt[kq + 14][rr], lt[kq + 15][rr]);
      u16* o = dst + (c0 + rr) * dstC + k0 + kq;
      *(uint4*)&o[0] = pa;
      *(uint4*)&o[8] = pb;
    }
  }
}

// ---------------- QKV: combined 3-mat bf16 GEMM via global_load_lds double-buffer ----------
__global__ __launch_bounds__(256) void qkv_mfma(
    const u16* __restrict__ xbT, const u16* __restrict__ Wcat,
    const float* __restrict__ bq, const float* __restrict__ bk, const float* __restrict__ bv,
    const float* __restrict__ bn1g, const float* __restrict__ bn1b, const float* __restrict__ p2b,
    u16* __restrict__ xqh, u16* __restrict__ xkh, float* __restrict__ xv) {
  __shared__ u32 Sh[2][5120];     // per buf: A rows 0..127 [0,2048), W rows 0..191 [2048,5120)
  const float rno = 1.0f / sqrtf(1.0f + 1e-5f);
  const int mt  = blockIdx.x;
  const int b   = mt >> 2;
  const int m0c = (mt & 3) * 128;
  const int j0  = blockIdx.y * 64;
  const int t   = threadIdx.x;
  const int lane = t & 63, w = t >> 6;
  const int l15 = lane & 15, quad = lane >> 4;

  // per-lane swizzled global sources (k0-invariant)
  const u16* asrc[2];
#pragma unroll
  for (int rd = 0; rd < 2; rd++) {
    const int gidx = rd * 256 + t;
    const int r = gidx >> 2, g = gidx & 3;
    const int gd = g ^ (r & 3) ^ ((r >> 2) & 3);
    asrc[rd] = xbT + (b * 512 + m0c + r) * 512 + gd * 8;
  }
  const u16* wsrc[3];
#pragma unroll
  for (int rd = 0; rd < 3; rd++) {
    const int gidx = rd * 256 + t;
    const int r = gidx >> 2, g = gidx & 3;
    const int gd = g ^ (r & 3) ^ ((r >> 2) & 3);
    wsrc[rd] = Wcat + (r >> 6) * 262144 + (j0 + (r & 63)) * 512 + gd * 8;
  }

  f32x4 acc[4][3][2];
#pragma unroll
  for (int a1 = 0; a1 < 4; a1++)
#pragma unroll
    for (int a2 = 0; a2 < 3; a2++)
#pragma unroll
      for (int a3 = 0; a3 < 2; a3++) acc[a1][a2][a3] = (f32x4){0.f, 0.f, 0.f, 0.f};

  const int sa  = (quad ^ (l15 & 3) ^ ((l15 >> 2) & 3)) * 4;  // read swizzle (u32 units)
  const int ra0 = ((2 * w + 0) * 16 + l15) * 16;
  const int ra1 = ((2 * w + 1) * 16 + l15) * 16;

  auto stage = [&](int buf, int k0) {
#pragma unroll
    for (int rd = 0; rd < 2; rd++)
      GLD_LDS16(asrc[rd] + k0, &Sh[buf][(rd * 256 + w * 64) * 4]);
#pragma unroll
    for (int rd = 0; rd < 3; rd++)
      GLD_LDS16(wsrc[rd] + k0, &Sh[buf][2048 + (rd * 256 + w * 64) * 4]);
  };
  auto mfma_step = [&](int buf) {
    const u32* S = Sh[buf];
    const bf16x8 a0 = *(const bf16x8*)&S[ra0 + sa];
    const bf16x8 a1 = *(const bf16x8*)&S[ra1 + sa];
#pragma unroll
    for (int js = 0; js < 4; js++)
#pragma unroll
      for (int mat = 0; mat < 3; mat++) {
        const bf16x8 bfr = *(const bf16x8*)&S[2048 + (mat * 64 + js * 16 + l15) * 16 + sa];
        acc[js][mat][0] = __builtin_amdgcn_mfma_f32_16x16x32_bf16(a0, bfr, acc[js][mat][0], 0, 0, 0);
        acc[js][mat][1] = __builtin_amdgcn_mfma_f32_16x16x32_bf16(a1, bfr, acc[js][mat][1], 0, 0, 0);
      }
  };

  stage(0, 0);
  asm volatile("s_waitcnt vmcnt(0)" ::: "memory");
  __syncthreads();
  int cur = 0;
  for (int k0 = 0; k0 < 512; k0 += 32) {
    if (k0 + 32 < 512) stage(cur ^ 1, k0 + 32);   // next chunk in flight across the MFMAs
    mfma_step(cur);
    asm volatile("s_waitcnt vmcnt(0)" ::: "memory");
    __syncthreads();
    cur ^= 1;
  }

  float bias[4][3], s1v[4], Tv[4];
#pragma unroll
  for (int js = 0; js < 4; js++) {
    const int col = j0 + js * 16 + l15;
    bias[js][0] = bq[col];
    bias[js][1] = bk[col];
    bias[js][2] = bv[col];
    s1v[js] = bn1g[col] * rno;
    Tv[js]  = fmaf(p2b[col], s1v[js], bn1b[col]);
  }
#pragma unroll
  for (int js = 0; js < 4; js++)
#pragma unroll
    for (int mat = 0; mat < 3; mat++) {
      const int col = j0 + js * 16 + l15;
#pragma unroll
      for (int st = 0; st < 2; st++) {
        const int rbase = b * 512 + m0c + (2 * w + st) * 16 + quad * 4;
        const f32x4 v = acc[js][mat][st];
        if (mat == 2) {
#pragma unroll
          for (int reg = 0; reg < 4; reg++)
            xv[(rbase + reg) * 512 + col] = v[reg] + bias[js][2];
        } else if (mat == 0) {
#pragma unroll
          for (int reg = 0; reg < 4; reg++)
            xqh[(rbase + reg) * 512 + col] = f2bf((v[reg] + bias[js][0]) * s1v[js] - Tv[js]);
        } else {
#pragma unroll
          for (int reg = 0; reg < 4; reg++)
            xkh[(rbase + reg) * 512 + col] = f2bf((v[reg] + bias[js][1]) * s1v[js]);
        }
      }
    }
}

// ---------------- fused attention v12: double-buffered wbf -> 1 barrier per K-chunk ----
// r12/r13 lessons: (256,5)/48VGPR no-spill is the sweet spot; only wbf is cross-wave.
// wbf[2] lets write(next) and read(cur) straddle ONE barrier: read(i)<bar(i)<write(i+1)
// and write(i)<bar(i)<read(i+1). t1 barriers 16 -> 8. LDS 31744 B -> still 5 blocks/CU.
// Arena ARN[7680] floats:
//   A0[512] A1[512] A2[512] [0,1536) | wbf0 [1536,3584) | wbf1 [3584,5632) | ubf [5632,7680)
//   lg float[64][66]=4224 overlays [0,4224)   (post-t2; tables/wbf dead)
#define NQ  4
#define LSd 66

__global__ __launch_bounds__(256, 5) void attn_kernel(
    const float* __restrict__ p, const int* __restrict__ idx,
    const u16* __restrict__ xqh, const u16* __restrict__ xkh, const float* __restrict__ xv,
    const float* __restrict__ p1W, const float* __restrict__ p1b,
    const float* __restrict__ pbg, const float* __restrict__ pbb,
    const float* __restrict__ p2W, const float* __restrict__ p2b,
    const float* __restrict__ bn1g, const float* __restrict__ bn1b,
    const u16* __restrict__ w1p, const float* __restrict__ w1b,
    const float* __restrict__ bn2g, const float* __restrict__ bn2b,
    const u16* __restrict__ w2p, const float* __restrict__ w2b,
    float* __restrict__ out) {
  const float rno = 1.0f / sqrtf(1.0f + 1e-5f);
  // XCD-aware swizzle: batch-pair per XCD so gathered xk/xv rows stay L2-resident
  const int s_  = blockIdx.x;
  const int xcd = s_ & 7, kk_ = s_ >> 3;
  const int b   = (xcd << 1) | (kk_ & 1);
  const int n0  = (kk_ >> 1) * NQ;
  const int t  = threadIdx.x;
  __shared__ float ARN[7680];
  __shared__ float h_s[64][3];
  __shared__ int   idx_s[64];
  float* A0f = ARN;
  float* A1f = ARN + 512;
  float* A2f = ARN + 1024;
  u32* wbf0 = (u32*)(ARN + 1536);
  u32* wbf1 = (u32*)(ARN + 3584);
  u32* ubf  = (u32*)(ARN + 5632);

  if (t < 64) idx_s[t] = idx[(b * Nv + n0 + (t >> 4)) * NSv + (t & 15)] & (Nv - 1);

  // w1/w2 staging geometry: granule g of LDS row r holds data octet g ^ (r&7)
  int wrow[2], wg[2], wgd[2];
#pragma unroll
  for (int rd = 0; rd < 2; rd++) {
    const int gidx = rd * 256 + t;
    wrow[rd] = gidx >> 3; wg[rd] = gidx & 7; wgd[rd] = wg[rd] ^ (wrow[rd] & 7);
  }
  // issue w1 chunk-0 loads early (latency hides under table + h_s compute)
  uint4 wr0[2];
#pragma unroll
  for (int rd = 0; rd < 2; rd++)
    wr0[rd] = *(const uint4*)&w1p[wrow[rd] * 512 + 0 + wgd[rd] * 8];

  // folded coefficient tables: A* = p2W_row * s1  (S,T folded into xkh/xqh upstream)
  {
    const int c0 = t * 2;
#pragma unroll
    for (int i = 0; i < 2; i++) {
      const int c = c0 + i;
      const float s1 = bn1g[c] * rno;
      A0f[c] = p2W[c] * s1;
      A1f[c] = p2W[512 + c] * s1;
      A2f[c] = p2W[1024 + c] * s1;
    }
  }
  __syncthreads();

  if (t < 192) {
    const int row = t / 3, j = t % 3;
    const int m = idx_s[row];
    const int n = n0 + (row >> 4);
    float d0 = p[(b * Nv + m) * 3 + 0] - p[(b * Nv + n) * 3 + 0];
    float d1 = p[(b * Nv + m) * 3 + 1] - p[(b * Nv + n) * 3 + 1];
    float d2 = p[(b * Nv + m) * 3 + 2] - p[(b * Nv + n) * 3 + 2];
    float y = d0 * p1W[0 * 3 + j] + d1 * p1W[1 * 3 + j] + d2 * p1W[2 * 3 + j] + p1b[j];
    y = y * (pbg[j] * rno) + pbb[j];
    h_s[row][j] = fmaxf(y, 0.0f);
  }

  // xk' / xq' chunk-0 prefetch, bf16 (idx_s valid after first barrier)
  const int row = t >> 2, ci = (t & 3) * 16;
  const int mrow = idx_s[row];
  const u16* xkr = xkh + (b * Nv + mrow) * Cv + ci;
  const u16* xqr = xqh + (b * Nv + n0 + (row >> 4)) * Cv + ci;
  uint4 pf[2], pfq[2];
#pragma unroll
  for (int i = 0; i < 2; i++) {
    pf[i]  = *(const uint4*)&xkr[i * 8];
    pfq[i] = *(const uint4*)&xqr[i * 8];
  }
  // stage w1 chunk-0 into wbf0 before the setup barrier (no extra barrier needed)
#pragma unroll
  for (int rd = 0; rd < 2; rd++)
    *(uint4*)&wbf0[wrow[rd] * 32 + wg[rd] * 4] = wr0[rd];
  __syncthreads();

  const int lane = t & 63, w = t >> 6;
  const int l15 = lane & 15, quad = lane >> 4;
  const float h0 = h_s[row][0], h1 = h_s[row][1], h2 = h_s[row][2];
  const int rsw = row & 7, g0 = (t & 3) * 2;

  f32x4 acc[4];
#pragma unroll
  for (int a2 = 0; a2 < 4; a2++) acc[a2] = (f32x4){0.f, 0.f, 0.f, 0.f};

  // ---- t1 = u(64x512) @ w1(512x64); wbf double-buffered, ONE barrier per K-chunk ----
  auto t1body = [&](int kc, u32* wcur, u32* wnxt, bool more) {
    uint4 wr[2];
    if (more) {
#pragma unroll
      for (int rd = 0; rd < 2; rd++)
        wr[rd] = *(const uint4*)&w1p[wrow[rd] * 512 + (kc + 64) + wgd[rd] * 8];
    }
    // u = relu((xk' - xq') + h0*A0 + h1*A1 + h2*A2), cvt_pk bf16, swizzled b128 store
    {
      u32* ub = &ubf[row * 32];
#pragma unroll
      for (int gi = 0; gi < 2; gi++) {
        const int c4 = kc + ci + gi * 8;
        const float4 A0a = *(const float4*)&A0f[c4], A0b = *(const float4*)&A0f[c4 + 4];
        const float4 A1a = *(const float4*)&A1f[c4], A1b = *(const float4*)&A1f[c4 + 4];
        const float4 A2a = *(const float4*)&A2f[c4], A2b = *(const float4*)&A2f[c4 + 4];
        const uint4 kw = pf[gi], qw = pfq[gi];
        const float d0 = bfl(kw.x) - bfl(qw.x);
        const float d1 = bfh(kw.x) - bfh(qw.x);
        const float d2 = bfl(kw.y) - bfl(qw.y);
        const float d3 = bfh(kw.y) - bfh(qw.y);
        const float d4 = bfl(kw.z) - bfl(qw.z);
        const float d5 = bfh(kw.z) - bfh(qw.z);
        const float d6 = bfl(kw.w) - bfl(qw.w);
        const float d7 = bfh(kw.w) - bfh(qw.w);
        const float u0 = fmaxf(fmaf(h0, A0a.x, fmaf(h1, A1a.x, fmaf(h2, A2a.x, d0))), 0.f);
        const float u1 = fmaxf(fmaf(h0, A0a.y, fmaf(h1, A1a.y, fmaf(h2, A2a.y, d1))), 0.f);
        const float u2 = fmaxf(fmaf(h0, A0a.z, fmaf(h1, A1a.z, fmaf(h2, A2a.z, d2))), 0.f);
        const float u3 = fmaxf(fmaf(h0, A0a.w, fmaf(h1, A1a.w, fmaf(h2, A2a.w, d3))), 0.f);
        const float u4 = fmaxf(fmaf(h0, A0b.x, fmaf(h1, A1b.x, fmaf(h2, A2b.x, d4))), 0.f);
        const float u5 = fmaxf(fmaf(h0, A0b.y, fmaf(h1, A1b.y, fmaf(h2, A2b.y, d5))), 0.f);
        const float u6 = fmaxf(fmaf(h0, A0b.z, fmaf(h1, A1b.z, fmaf(h2, A2b.z, d6))), 0.f);
        const float u7 = fmaxf(fmaf(h0, A0b.w, fmaf(h1, A1b.w, fmaf(h2, A2b.w, d7))), 0.f);
        uint4 pk;
        pk.x = cvtpk(u0, u1); pk.y = cvtpk(u2, u3);
        pk.z = cvtpk(u4, u5); pk.w = cvtpk(u6, u7);
        *(uint4*)&ub[((g0 + gi) ^ rsw) * 4] = pk;
      }
    }
    // prefetch next xk'/xq' chunk + write staged w1 into the OTHER buffer
    if (more) {
#pragma unroll
      for (int i = 0; i < 2; i++) {
        pf[i]  = *(const uint4*)&xkr[kc + 64 + i * 8];
        pfq[i] = *(const uint4*)&xqr[kc + 64 + i * 8];
      }
#pragma unroll
      for (int rd = 0; rd < 2; rd++)
        *(uint4*)&wnxt[wrow[rd] * 32 + wg[rd] * 4] = wr[rd];
    }
    // MFMA reads ubf (wave-private, lgkm-ordered) + wcur (staged before previous barrier)
#pragma unroll
    for (int ks = 0; ks < 2; ks++) {
      const int sw = ((ks * 4 + quad) ^ (l15 & 7)) * 4;
      const bf16x8 a0 = *(const bf16x8*)&ubf[(w * 16 + l15) * 32 + sw];
#pragma unroll
      for (int js = 0; js < 4; js++) {
        const bf16x8 bfr = *(const bf16x8*)&wcur[(js * 16 + l15) * 32 + sw];
        acc[js] = __builtin_amdgcn_mfma_f32_16x16x32_bf16(a0, bfr, acc[js], 0, 0, 0);
      }
    }
    __syncthreads();
  };
#pragma unroll 1
  for (int kc2 = 0; kc2 < 512; kc2 += 128) {
    t1body(kc2,      wbf0, wbf1, true);
    t1body(kc2 + 64, wbf1, wbf0, kc2 + 128 < 512);
  }

  // ---- r1 = relu(bn2(t1 + w1b)) -> bf16 A-layout (swizzled); stage pre-packed w2 ----
  {
    u16* r1h = (u16*)ubf;
#pragma unroll
    for (int js = 0; js < 4; js++) {
      const int j = js * 16 + l15;
      const float wb = w1b[j], s2 = bn2g[j] * rno, b2 = bn2b[j];
      const int gph = j >> 3;
      const int rbase = w * 16 + quad * 4;
#pragma unroll
      for (int reg = 0; reg < 4; reg++) {
        const int r = rbase + reg;
        const float v = fmaxf((acc[js][reg] + wb) * s2 + b2, 0.f);
        r1h[r * 64 + (gph ^ (r & 7)) * 8 + (j & 7)] = f2bf(v);
      }
    }
  }
#pragma unroll
  for (int rd = 0; rd < 2; rd++) {
    const uint4 v = *(const uint4*)&w2p[wrow[rd] * 64 + wgd[rd] * 8];
    *(uint4*)&wbf0[wrow[rd] * 32 + wg[rd] * 4] = v;
  }
  __syncthreads();

  // ---- t2 = r1(64x64) @ w2(64x64) via MFMA (w2 in wbf0) ----
  f32x4 acc2[4];
#pragma unroll
  for (int a2 = 0; a2 < 4; a2++) acc2[a2] = (f32x4){0.f, 0.f, 0.f, 0.f};
#pragma unroll
  for (int ks = 0; ks < 2; ks++) {
    const int sw = ((ks * 4 + quad) ^ (l15 & 7)) * 4;
    const bf16x8 a0 = *(const bf16x8*)&ubf[(w * 16 + l15) * 32 + sw];
#pragma unroll
    for (int js = 0; js < 4; js++) {
      const bf16x8 bfr = *(const bf16x8*)&wbf0[(js * 16 + l15) * 32 + sw];
      acc2[js] = __builtin_amdgcn_mfma_f32_16x16x32_bf16(a0, bfr, acc2[js], 0, 0, 0);
    }
  }
  __syncthreads();   // tables / wbf / r1 dead past here; lg overlays them

  // ---- logits -> lg[row][j] (fp32, stride 66) ----
  {
    float* lg = ARN;
#pragma unroll
    for (int js = 0; js < 4; js++) {
      const float wb2 = w2b[js * 16 + l15];
      const int rbase = w * 16 + quad * 4;
#pragma unroll
      for (int reg = 0; reg < 4; reg++)
        lg[(rbase + reg) * LSd + js * 16 + l15] = acc2[js][reg] + wb2;
    }
  }
  __syncthreads();

  // ---- softmax over the 16 neighbors: one (q, jj) per thread ----
  {
    const int q = t >> 6, jj = t & 63;
    float* base = &ARN[(q * 16) * LSd + jj];
    float v[NSv];
#pragma unroll
    for (int k = 0; k < NSv; k++) v[k] = base[k * LSd];
    float mx = v[0];
#pragma unroll
    for (int k = 1; k < NSv; k++) mx = fmaxf(mx, v[k]);
    float s = 0.0f;
#pragma unroll
    for (int k = 0; k < NSv; k++) { v[k] = __expf(v[k] - mx); s += v[k]; }
    const float is = 1.0f / s;
#pragma unroll
    for (int k = 0; k < NSv; k++) base[k * LSd] = v[k] * is;
  }
  __syncthreads();

  // ---- out[q][c]: H-fold. sum_k sm*pr == pa*H0 + pb*H1 + pc*H2 + pd (sum sm = 1) ----
  {
    const int q = t >> 6, cb = t & 63;
    int mk[NSv];
    float smv[NSv];
    float H0 = 0.f, H1 = 0.f, H2 = 0.f;
    const float* smb = &ARN[(q * 16) * LSd];
#pragma unroll
    for (int k = 0; k < NSv; k++) {
      mk[k] = idx_s[q * 16 + k];
      const float s0 = smb[k * LSd + cb];
      smv[k] = s0;
      H0 = fmaf(h_s[q * 16 + k][0], s0, H0);
      H1 = fmaf(h_s[q * 16 + k][1], s0, H1);
      H2 = fmaf(h_s[q * 16 + k][2], s0, H2);
    }
    float* ob = out + (b * Nv + n0 + q) * Cv;
    const float* xvb = xv + b * Nv * Cv;
#pragma unroll 1
    for (int ii = 0; ii < 8; ii++) {
      const int c = cb + ii * 64;
      float s0 = 0.f, s1 = 0.f, s2 = 0.f, s3 = 0.f;
#pragma unroll
      for (int k = 0; k < NSv; k += 4) {
        s0 = fmaf(xvb[mk[k + 0] * Cv + c], smv[k + 0], s0);
        s1 = fmaf(xvb[mk[k + 1] * Cv + c], smv[k + 1], s1);
        s2 = fmaf(xvb[mk[k + 2] * Cv + c], smv[k + 2], s2);
        s3 = fmaf(xvb[mk[k + 3] * Cv + c], smv[k + 3], s3);
      }
      float r = (s0 + s1) + (s2 + s3);
      r = fmaf(p2W[c], H0, r);
      r = fmaf(p2W[512 + c], H1, r);
      r = fmaf(p2W[1024 + c], H2, r);
      ob[c] = r + p2b[c];
    }
  }
}

extern "C" void kernel_launch(void* const* d_in, const int* in_sizes, int n_in,
                              void* d_out, int out_size, void* d_ws, size_t ws_size,
                              hipStream_t stream) {
  const float* p    = (const float*)d_in[0];
  const float* x    = (const float*)d_in[1];
  const float* Wq   = (const float*)d_in[2];
  const float* bq   = (const float*)d_in[3];
  const float* Wk   = (const float*)d_in[4];
  const float* bk   = (const float*)d_in[5];
  const float* Wv   = (const float*)d_in[6];
  const float* bv   = (const float*)d_in[7];
  const float* p1W  = (const float*)d_in[8];
  const float* p1b  = (const float*)d_in[9];
  const float* pbg  = (const float*)d_in[10];
  const float* pbb  = (const float*)d_in[11];
  const float* p2W  = (const float*)d_in[12];
  const float* p2b  = (const float*)d_in[13];
  const float* bn1g = (const float*)d_in[14];
  const float* bn1b = (const float*)d_in[15];
  const float* w1W  = (const float*)d_in[16];
  const float* w1b  = (const float*)d_in[17];
  const float* bn2g = (const float*)d_in[18];
  const float* bn2b = (const float*)d_in[19];
  const float* w2W  = (const float*)d_in[20];
  const float* w2b  = (const float*)d_in[21];

  // ws layout (bytes): idx int [0, 512 KiB) | xv fp32 16 MiB | xqh/xkh bf16 8 MiB each |
  //   xbT bf16 8 MiB | Wcat bf16 1.5 MiB | w1p 64 KiB | w2p 8 KiB  -> ~42 MiB total
  int*   idxb = (int*)d_ws;
  float* xv   = (float*)((char*)d_ws + 524288);
  u16*   xqh  = (u16*)(xv + 8192 * 512);
  u16*   xkh  = xqh + 8192 * 512;
  u16*   xbT  = xkh + 8192 * 512;
  u16*   Wcat = xbT + 8192 * 512;
  u16*   w1p  = Wcat + 3 * 512 * 512;
  u16*   w2p  = w1p + 64 * 512;

  prep_kernel<<<dim3(1536), 256, 0, stream>>>(p, idxb, x, Wq, Wk, Wv, w1W, w2W,
                                              xbT, Wcat, w1p, w2p);
  qkv_mfma<<<dim3(64, 8), 256, 0, stream>>>(xbT, Wcat, bq, bk, bv, bn1g, bn1b, p2b,
                                            xqh, xkh, xv);
  attn_kernel<<<dim3(2048), 256, 0, stream>>>(p, idxb, xqh, xkh, xv,
                                              p1W, p1b, pbg, pbb, p2W, p2b,
                                              bn1g, bn1b, w1p, w1b, bn2g, bn2b,
                                              w2p, w2b, (float*)d_out);
}

// Round 15
// 215.900 us; speedup vs baseline: 1.1497x; 1.1497x over previous
//
#include <hip/hip_runtime.h>

typedef unsigned short u16;
typedef unsigned int   u32;

#define Bv  16
#define Nv  512
#define Cv  512
#define NSv 16
#define CCv 64

typedef __attribute__((ext_vector_type(8))) short bf16x8;
typedef __attribute__((ext_vector_type(4))) float f32x4;

__device__ __forceinline__ u16 f2bf(float f) {   // RNE fp32 -> bf16
  u32 b = __float_as_uint(f);
  return (u16)((b + 0x7fffu + ((b >> 16) & 1u)) >> 16);
}
__device__ __forceinline__ u32 pack2(float lo, float hi) {
  return (u32)f2bf(lo) | ((u32)f2bf(hi) << 16);
}
__device__ __forceinline__ u32 cvtpk(float lo, float hi) {  // 1-instr RNE pack (T12 recipe)
  u32 r;
  asm("v_cvt_pk_bf16_f32 %0, %1, %2" : "=v"(r) : "v"(lo), "v"(hi));
  return r;
}
__device__ __forceinline__ float bfl(u32 w) { return __uint_as_float(w << 16); }
__device__ __forceinline__ float bfh(u32 w) { return __uint_as_float(w & 0xffff0000u); }

// global -> LDS direct (16B/lane); LDS dest must be wave-uniform base, lane i lands at +16*i
#define GLD_LDS16(gp, lp)                                                              \
  __builtin_amdgcn_global_load_lds(                                                    \
      (const __attribute__((address_space(1))) u32*)(const void*)(gp),                 \
      (__attribute__((address_space(3))) u32*)(lp), 16, 0, 0)

// ---------------- prep: knn (blocks 0..255, full-chip) + cvt (blocks 256..1535) ----------
// knn: 8 lanes/query x 64 candidates, reg-resident ripple-16, tournament merge via shfl.
// Output is the top-16 SET (order-free: all downstream NS-axis ops are symmetric).
__global__ __launch_bounds__(256) void prep_kernel(
    const float* __restrict__ p, int* __restrict__ idx_out,
    const float* __restrict__ x,
    const float* __restrict__ Wq, const float* __restrict__ Wk, const float* __restrict__ Wv,
    const float* __restrict__ w1W, const float* __restrict__ w2W,
    u16* __restrict__ xbT, u16* __restrict__ Wcat,
    u16* __restrict__ w1p, u16* __restrict__ w2p) {
  __shared__ __align__(16) char ARB[16640];   // knn: pnts 8 KB; cvt: lt 16.6 KB
  const int t = threadIdx.x;
  if (blockIdx.x < 256) {
#pragma clang fp contract(off)
    float4* pnts = (float4*)ARB;
    const int b  = blockIdx.x >> 4;
    const int q0 = (blockIdx.x & 15) * 32;
    for (int e = t; e < Nv; e += 256) {
      float xx = p[(b * Nv + e) * 3 + 0];
      float yy = p[(b * Nv + e) * 3 + 1];
      float zz = p[(b * Nv + e) * 3 + 2];
      float s = ((xx * xx) + (yy * yy)) + (zz * zz);
      pnts[e] = make_float4(xx, yy, zz, s);
    }
    __syncthreads();
    const int q  = q0 + (t >> 3);   // 32 queries/block, 8 lanes each
    const int pt = t & 7;           // candidate part: m in [pt*64, pt*64+64)
    const float4 qp = pnts[q];
    float bd[NSv]; int bi[NSv];
#pragma unroll
    for (int i = 0; i < NSv; i++) { bd[i] = 1e30f; bi[i] = 0; }
    const int m0 = pt * 64;
#pragma unroll 1
    for (int i = 0; i < 64; i++) {
      const int m = m0 + i;
      const float4 c = pnts[m];
      float dot = __builtin_fmaf(qp.z, c.z, __builtin_fmaf(qp.y, c.y, qp.x * c.x));
      float d = (qp.w + c.w) - (2.0f * dot);
      bool cm[NSv];
#pragma unroll
      for (int j = 0; j < NSv; j++) cm[j] = bd[j] > d;
#pragma unroll
      for (int j = NSv - 1; j > 0; j--) {
        bd[j] = cm[j - 1] ? bd[j - 1] : (cm[j] ? d : bd[j]);
        bi[j] = cm[j - 1] ? bi[j - 1] : (cm[j] ? m : bi[j]);
      }
      bd[0] = cm[0] ? d : bd[0];
      bi[0] = cm[0] ? m : bi[0];
    }
    // tournament merge: 16 pops; ties -> lower part (= lower m, matches top_k tie-break)
    int h = 0;
#pragma unroll 1
    for (int s = 0; s < 16; s++) {
      float mv = bd[0]; int ml = pt;
      {
        float ov = __shfl_xor(mv, 1); int ol = __shfl_xor(ml, 1);
        bool tk = (ov < mv) || (ov == mv && ol < ml);
        mv = tk ? ov : mv; ml = tk ? ol : ml;
      }
      {
        float ov = __shfl_xor(mv, 2); int ol = __shfl_xor(ml, 2);
        bool tk = (ov < mv) || (ov == mv && ol < ml);
        mv = tk ? ov : mv; ml = tk ? ol : ml;
      }
      {
        float ov = __shfl_xor(mv, 4); int ol = __shfl_xor(ml, 4);
        bool tk = (ov < mv) || (ov == mv && ol < ml);
        mv = tk ? ov : mv; ml = tk ? ol : ml;
      }
      if (ml == pt) {   // I own the min: pop head (shift value list; bi stays in place)
#pragma unroll
        for (int j = 0; j < 15; j++) bd[j] = bd[j + 1];
        bd[15] = 1e30f;
        h++;
      }
    }
    // exclusive prefix of h over the 8-lane group -> output offset
    const int lane = t & 63, gbase = lane & 56;
    int pre = 0;
#pragma unroll
    for (int j = 0; j < 7; j++) {
      int hj = __shfl(h, gbase + j);
      if (j < pt) pre += hj;
    }
    int* o = idx_out + (b * Nv + q) * NSv + pre;
#pragma unroll
    for (int j = 0; j < 16; j++)
      if (j < h) o[j] = bi[j];
  } else {
    // ---- cvt: fp32 -> bf16 transpose/convert ----
    float (*lt)[65] = (float(*)[65])ARB;
    const int id = blockIdx.x - 256;
    const int tile = id & 63, unit = id >> 6;
    const float* src; u16* dst;
    int k0, c0, srcC, dstC;
    if (unit < 16) {
      src = x + unit * 262144; dst = xbT + unit * 262144;
      k0 = (tile & 7) * 64; c0 = (tile >> 3) * 64; srcC = 512; dstC = 512;
    } else if (unit < 19) {
      const int mat = unit - 16;
      src = (mat == 0) ? Wq : (mat == 1) ? Wk : Wv;
      dst = Wcat + mat * 262144;
      k0 = (tile & 7) * 64; c0 = (tile >> 3) * 64; srcC = 512; dstC = 512;
    } else {
      if (tile < 8)       { src = w1W; dst = w1p; k0 = tile * 64; c0 = 0; srcC = 64; dstC = 512; }
      else if (tile == 8) { src = w2W; dst = w2p; k0 = 0; c0 = 0; srcC = 64; dstC = 64; }
      else return;
    }
    {
      const int r = t >> 2, cq = (t & 3) * 16;
      const float* s = src + (k0 + r) * srcC + c0 + cq;
#pragma unroll
      for (int i = 0; i < 4; i++) {
        const float4 v = *(const float4*)&s[i * 4];
        lt[r][cq + i * 4 + 0] = v.x;
        lt[r][cq + i * 4 + 1] = v.y;
        lt[r][cq + i * 4 + 2] = v.z;
        lt[r][cq + i * 4 + 3] = v.w;
      }
    }
    __syncthreads();
    {
      const int rr = t >> 2, kq = (t & 3) * 16;
      uint4 pa, pb;
      pa.x = pack2(lt[kq + 0][rr],  lt[kq + 1][rr]);
      pa.y = pack2(lt[kq + 2][rr],  lt[kq + 3][rr]);
      pa.z = pack2(lt[kq + 4][rr],  lt[kq + 5][rr]);
      pa.w = pack2(lt[kq + 6][rr],  lt[kq + 7][rr]);
      pb.x = pack2(lt[kq + 8][rr],  lt[kq + 9][rr]);
      pb.y = pack2(lt[kq + 10][rr], lt[kq + 11][rr]);
      pb.z = pack2(lt[kq + 12][rr], lt[kq + 13][rr]);
      pb.w = pack2(lt[kq + 14][rr], lt[kq + 15][rr]);
      u16* o = dst + (c0 + rr) * dstC + k0 + kq;
      *(uint4*)&o[0] = pa;
      *(uint4*)&o[8] = pb;
    }
  }
}

// ---------------- QKV: combined 3-mat bf16 GEMM via global_load_lds double-buffer ----------
__global__ __launch_bounds__(256) void qkv_mfma(
    const u16* __restrict__ xbT, const u16* __restrict__ Wcat,
    const float* __restrict__ bq, const float* __restrict__ bk, const float* __restrict__ bv,
    const float* __restrict__ bn1g, const float* __restrict__ bn1b, const float* __restrict__ p2b,
    u16* __restrict__ xqh, u16* __restrict__ xkh, float* __restrict__ xv) {
  __shared__ u32 Sh[2][5120];     // per buf: A rows 0..127 [0,2048), W rows 0..191 [2048,5120)
  const float rno = 1.0f / sqrtf(1.0f + 1e-5f);
  const int mt  = blockIdx.x;
  const int b   = mt >> 2;
  const int m0c = (mt & 3) * 128;
  const int j0  = blockIdx.y * 64;
  const int t   = threadIdx.x;
  const int lane = t & 63, w = t >> 6;
  const int l15 = lane & 15, quad = lane >> 4;

  // per-lane swizzled global sources (k0-invariant)
  const u16* asrc[2];
#pragma unroll
  for (int rd = 0; rd < 2; rd++) {
    const int gidx = rd * 256 + t;
    const int r = gidx >> 2, g = gidx & 3;
    const int gd = g ^ (r & 3) ^ ((r >> 2) & 3);
    asrc[rd] = xbT + (b * 512 + m0c + r) * 512 + gd * 8;
  }
  const u16* wsrc[3];
#pragma unroll
  for (int rd = 0; rd < 3; rd++) {
    const int gidx = rd * 256 + t;
    const int r = gidx >> 2, g = gidx & 3;
    const int gd = g ^ (r & 3) ^ ((r >> 2) & 3);
    wsrc[rd] = Wcat + (r >> 6) * 262144 + (j0 + (r & 63)) * 512 + gd * 8;
  }

  f32x4 acc[4][3][2];
#pragma unroll
  for (int a1 = 0; a1 < 4; a1++)
#pragma unroll
    for (int a2 = 0; a2 < 3; a2++)
#pragma unroll
      for (int a3 = 0; a3 < 2; a3++) acc[a1][a2][a3] = (f32x4){0.f, 0.f, 0.f, 0.f};

  const int sa  = (quad ^ (l15 & 3) ^ ((l15 >> 2) & 3)) * 4;  // read swizzle (u32 units)
  const int ra0 = ((2 * w + 0) * 16 + l15) * 16;
  const int ra1 = ((2 * w + 1) * 16 + l15) * 16;

  auto stage = [&](int buf, int k0) {
#pragma unroll
    for (int rd = 0; rd < 2; rd++)
      GLD_LDS16(asrc[rd] + k0, &Sh[buf][(rd * 256 + w * 64) * 4]);
#pragma unroll
    for (int rd = 0; rd < 3; rd++)
      GLD_LDS16(wsrc[rd] + k0, &Sh[buf][2048 + (rd * 256 + w * 64) * 4]);
  };
  auto mfma_step = [&](int buf) {
    const u32* S = Sh[buf];
    const bf16x8 a0 = *(const bf16x8*)&S[ra0 + sa];
    const bf16x8 a1 = *(const bf16x8*)&S[ra1 + sa];
#pragma unroll
    for (int js = 0; js < 4; js++)
#pragma unroll
      for (int mat = 0; mat < 3; mat++) {
        const bf16x8 bfr = *(const bf16x8*)&S[2048 + (mat * 64 + js * 16 + l15) * 16 + sa];
        acc[js][mat][0] = __builtin_amdgcn_mfma_f32_16x16x32_bf16(a0, bfr, acc[js][mat][0], 0, 0, 0);
        acc[js][mat][1] = __builtin_amdgcn_mfma_f32_16x16x32_bf16(a1, bfr, acc[js][mat][1], 0, 0, 0);
      }
  };

  stage(0, 0);
  asm volatile("s_waitcnt vmcnt(0)" ::: "memory");
  __syncthreads();
  int cur = 0;
  for (int k0 = 0; k0 < 512; k0 += 32) {
    if (k0 + 32 < 512) stage(cur ^ 1, k0 + 32);   // next chunk in flight across the MFMAs
    mfma_step(cur);
    asm volatile("s_waitcnt vmcnt(0)" ::: "memory");
    __syncthreads();
    cur ^= 1;
  }

  float bias[4][3], s1v[4], Tv[4];
#pragma unroll
  for (int js = 0; js < 4; js++) {
    const int col = j0 + js * 16 + l15;
    bias[js][0] = bq[col];
    bias[js][1] = bk[col];
    bias[js][2] = bv[col];
    s1v[js] = bn1g[col] * rno;
    Tv[js]  = fmaf(p2b[col], s1v[js], bn1b[col]);
  }
#pragma unroll
  for (int js = 0; js < 4; js++)
#pragma unroll
    for (int mat = 0; mat < 3; mat++) {
      const int col = j0 + js * 16 + l15;
#pragma unroll
      for (int st = 0; st < 2; st++) {
        const int rbase = b * 512 + m0c + (2 * w + st) * 16 + quad * 4;
        const f32x4 v = acc[js][mat][st];
        if (mat == 2) {
#pragma unroll
          for (int reg = 0; reg < 4; reg++)
            xv[(rbase + reg) * 512 + col] = v[reg] + bias[js][2];
        } else if (mat == 0) {
#pragma unroll
          for (int reg = 0; reg < 4; reg++)
            xqh[(rbase + reg) * 512 + col] = f2bf((v[reg] + bias[js][0]) * s1v[js] - Tv[js]);
        } else {
#pragma unroll
          for (int reg = 0; reg < 4; reg++)
            xkh[(rbase + reg) * 512 + col] = f2bf((v[reg] + bias[js][1]) * s1v[js]);
        }
      }
    }
}

// ---------------- fused attention v9 (r13, best known): NQ=4 tile @ (256,5), no spills ----
// r11: B-frags from global -> L2 latency on MFMA chain (-86%). r12: (256,6) -> spills (-33%).
// r14: lambda/dbuf wbf -> capture-by-ref arrays demoted to scratch, 80MB spill (-67%).
// This exact structure measured 49.2us attn / 216.4us total. Do not restructure.
// Arena ARN[5632] floats (22528 B):
//   A0[512] A1[512] A2[512]  [0,1536) | wbf u32[64*32] [1536,3584) | ubf u32[64*32] [3584,5632)
//   lg float[64][66] = 4224 overlays [0,4224)   (post-t2)
#define NQ  4
#define LSd 66

__global__ __launch_bounds__(256, 5) void attn_kernel(
    const float* __restrict__ p, const int* __restrict__ idx,
    const u16* __restrict__ xqh, const u16* __restrict__ xkh, const float* __restrict__ xv,
    const float* __restrict__ p1W, const float* __restrict__ p1b,
    const float* __restrict__ pbg, const float* __restrict__ pbb,
    const float* __restrict__ p2W, const float* __restrict__ p2b,
    const float* __restrict__ bn1g, const float* __restrict__ bn1b,
    const u16* __restrict__ w1p, const float* __restrict__ w1b,
    const float* __restrict__ bn2g, const float* __restrict__ bn2b,
    const u16* __restrict__ w2p, const float* __restrict__ w2b,
    float* __restrict__ out) {
  const float rno = 1.0f / sqrtf(1.0f + 1e-5f);
  // XCD-aware swizzle: batch-pair per XCD so gathered xk/xv rows stay L2-resident
  const int s_  = blockIdx.x;
  const int xcd = s_ & 7, kk_ = s_ >> 3;
  const int b   = (xcd << 1) | (kk_ & 1);
  const int n0  = (kk_ >> 1) * NQ;
  const int t  = threadIdx.x;
  __shared__ float ARN[5632];
  __shared__ float h_s[64][3];
  __shared__ int   idx_s[64];
  float* A0f = ARN;
  float* A1f = ARN + 512;
  float* A2f = ARN + 1024;
  u32* wbf = (u32*)(ARN + 1536);
  u32* ubf = (u32*)(ARN + 3584);

  if (t < 64) idx_s[t] = idx[(b * Nv + n0 + (t >> 4)) * NSv + (t & 15)] & (Nv - 1);

  // folded coefficient tables: A* = p2W_row * s1  (S,T folded into xkh/xqh upstream)
  {
    const int c0 = t * 2;
#pragma unroll
    for (int i = 0; i < 2; i++) {
      const int c = c0 + i;
      const float s1 = bn1g[c] * rno;
      A0f[c] = p2W[c] * s1;
      A1f[c] = p2W[512 + c] * s1;
      A2f[c] = p2W[1024 + c] * s1;
    }
  }
  __syncthreads();

  if (t < 192) {
    const int row = t / 3, j = t % 3;
    const int m = idx_s[row];
    const int n = n0 + (row >> 4);
    float d0 = p[(b * Nv + m) * 3 + 0] - p[(b * Nv + n) * 3 + 0];
    float d1 = p[(b * Nv + m) * 3 + 1] - p[(b * Nv + n) * 3 + 1];
    float d2 = p[(b * Nv + m) * 3 + 2] - p[(b * Nv + n) * 3 + 2];
    float y = d0 * p1W[0 * 3 + j] + d1 * p1W[1 * 3 + j] + d2 * p1W[2 * 3 + j] + p1b[j];
    y = y * (pbg[j] * rno) + pbb[j];
    h_s[row][j] = fmaxf(y, 0.0f);
  }

  // xk' / xq' chunk-0 prefetch, bf16 (idx_s valid after first barrier)
  const int row = t >> 2, ci = (t & 3) * 16;
  const int mrow = idx_s[row];
  const u16* xkr = xkh + (b * Nv + mrow) * Cv + ci;
  const u16* xqr = xqh + (b * Nv + n0 + (row >> 4)) * Cv + ci;
  uint4 pf[2], pfq[2];
#pragma unroll
  for (int i = 0; i < 2; i++) {
    pf[i]  = *(const uint4*)&xkr[i * 8];
    pfq[i] = *(const uint4*)&xqr[i * 8];
  }
  __syncthreads();

  const int lane = t & 63, w = t >> 6;
  const int l15 = lane & 15, quad = lane >> 4;
  const float h0 = h_s[row][0], h1 = h_s[row][1], h2 = h_s[row][2];
  const int rsw = row & 7, g0 = (t & 3) * 2;

  // w1/w2 staging geometry: granule g of LDS row r holds data octet g ^ (r&7)
  int wrow[2], wg[2], wgd[2];
#pragma unroll
  for (int rd = 0; rd < 2; rd++) {
    const int gidx = rd * 256 + t;
    wrow[rd] = gidx >> 3; wg[rd] = gidx & 7; wgd[rd] = wg[rd] ^ (wrow[rd] & 7);
  }

  f32x4 acc[4];
#pragma unroll
  for (int a2 = 0; a2 < 4; a2++) acc[a2] = (f32x4){0.f, 0.f, 0.f, 0.f};

  // ---- t1 = u(64x512) @ w1(512x64) via MFMA, K-chunks of 64 ----
  for (int kc = 0; kc < Cv; kc += 64) {
    // issue pre-packed bf16 w1 loads early (consumed after the VALU-heavy u-compute)
    uint4 wr[2];
#pragma unroll
    for (int rd = 0; rd < 2; rd++)
      wr[rd] = *(const uint4*)&w1p[wrow[rd] * 512 + kc + wgd[rd] * 8];
    // u = relu((xk' - xq') + h0*A0 + h1*A1 + h2*A2), cvt_pk bf16, swizzled b128 store
    {
      u32* ub = &ubf[row * 32];
#pragma unroll
      for (int gi = 0; gi < 2; gi++) {
        const int c4 = kc + ci + gi * 8;
        const float4 A0a = *(const float4*)&A0f[c4], A0b = *(const float4*)&A0f[c4 + 4];
        const float4 A1a = *(const float4*)&A1f[c4], A1b = *(const float4*)&A1f[c4 + 4];
        const float4 A2a = *(const float4*)&A2f[c4], A2b = *(const float4*)&A2f[c4 + 4];
        const uint4 kw = pf[gi], qw = pfq[gi];
        const float d0 = bfl(kw.x) - bfl(qw.x);
        const float d1 = bfh(kw.x) - bfh(qw.x);
        const float d2 = bfl(kw.y) - bfl(qw.y);
        const float d3 = bfh(kw.y) - bfh(qw.y);
        const float d4 = bfl(kw.z) - bfl(qw.z);
        const float d5 = bfh(kw.z) - bfh(qw.z);
        const float d6 = bfl(kw.w) - bfl(qw.w);
        const float d7 = bfh(kw.w) - bfh(qw.w);
        const float u0 = fmaxf(fmaf(h0, A0a.x, fmaf(h1, A1a.x, fmaf(h2, A2a.x, d0))), 0.f);
        const float u1 = fmaxf(fmaf(h0, A0a.y, fmaf(h1, A1a.y, fmaf(h2, A2a.y, d1))), 0.f);
        const float u2 = fmaxf(fmaf(h0, A0a.z, fmaf(h1, A1a.z, fmaf(h2, A2a.z, d2))), 0.f);
        const float u3 = fmaxf(fmaf(h0, A0a.w, fmaf(h1, A1a.w, fmaf(h2, A2a.w, d3))), 0.f);
        const float u4 = fmaxf(fmaf(h0, A0b.x, fmaf(h1, A1b.x, fmaf(h2, A2b.x, d4))), 0.f);
        const float u5 = fmaxf(fmaf(h0, A0b.y, fmaf(h1, A1b.y, fmaf(h2, A2b.y, d5))), 0.f);
        const float u6 = fmaxf(fmaf(h0, A0b.z, fmaf(h1, A1b.z, fmaf(h2, A2b.z, d6))), 0.f);
        const float u7 = fmaxf(fmaf(h0, A0b.w, fmaf(h1, A1b.w, fmaf(h2, A2b.w, d7))), 0.f);
        uint4 pk;
        pk.x = cvtpk(u0, u1); pk.y = cvtpk(u2, u3);
        pk.z = cvtpk(u4, u5); pk.w = cvtpk(u6, u7);
        *(uint4*)&ub[((g0 + gi) ^ rsw) * 4] = pk;
      }
    }
    // prefetch next xk'/xq' chunk (bf16, in flight across barrier + MFMA)
    if (kc + 64 < Cv) {
#pragma unroll
      for (int i = 0; i < 2; i++) {
        pf[i]  = *(const uint4*)&xkr[kc + 64 + i * 8];
        pfq[i] = *(const uint4*)&xqr[kc + 64 + i * 8];
      }
    }
    // write staged w1 chunk (swizzled)
#pragma unroll
    for (int rd = 0; rd < 2; rd++)
      *(uint4*)&wbf[wrow[rd] * 32 + wg[rd] * 4] = wr[rd];
    __syncthreads();
#pragma unroll
    for (int ks = 0; ks < 2; ks++) {
      const int sw = ((ks * 4 + quad) ^ (l15 & 7)) * 4;
      const bf16x8 a0 = *(const bf16x8*)&ubf[(w * 16 + l15) * 32 + sw];
#pragma unroll
      for (int js = 0; js < 4; js++) {
        const bf16x8 bfr = *(const bf16x8*)&wbf[(js * 16 + l15) * 32 + sw];
        acc[js] = __builtin_amdgcn_mfma_f32_16x16x32_bf16(a0, bfr, acc[js], 0, 0, 0);
      }
    }
    __syncthreads();
  }

  // ---- r1 = relu(bn2(t1 + w1b)) -> bf16 A-layout (swizzled); stage pre-packed w2 ----
  {
    u16* r1h = (u16*)ubf;
#pragma unroll
    for (int js = 0; js < 4; js++) {
      const int j = js * 16 + l15;
      const float wb = w1b[j], s2 = bn2g[j] * rno, b2 = bn2b[j];
      const int gph = j >> 3;
      const int rbase = w * 16 + quad * 4;
#pragma unroll
      for (int reg = 0; reg < 4; reg++) {
        const int r = rbase + reg;
        const float v = fmaxf((acc[js][reg] + wb) * s2 + b2, 0.f);
        r1h[r * 64 + (gph ^ (r & 7)) * 8 + (j & 7)] = f2bf(v);
      }
    }
  }
#pragma unroll
  for (int rd = 0; rd < 2; rd++) {
    const uint4 v = *(const uint4*)&w2p[wrow[rd] * 64 + wgd[rd] * 8];
    *(uint4*)&wbf[wrow[rd] * 32 + wg[rd] * 4] = v;
  }
  __syncthreads();

  // ---- t2 = r1(64x64) @ w2(64x64) via MFMA ----
  f32x4 acc2[4];
#pragma unroll
  for (int a2 = 0; a2 < 4; a2++) acc2[a2] = (f32x4){0.f, 0.f, 0.f, 0.f};
#pragma unroll
  for (int ks = 0; ks < 2; ks++) {
    const int sw = ((ks * 4 + quad) ^ (l15 & 7)) * 4;
    const bf16x8 a0 = *(const bf16x8*)&ubf[(w * 16 + l15) * 32 + sw];
#pragma unroll
    for (int js = 0; js < 4; js++) {
      const bf16x8 bfr = *(const bf16x8*)&wbf[(js * 16 + l15) * 32 + sw];
      acc2[js] = __builtin_amdgcn_mfma_f32_16x16x32_bf16(a0, bfr, acc2[js], 0, 0, 0);
    }
  }
  __syncthreads();   // tables / wbf / r1 dead past here; lg overlays them

  // ---- logits -> lg[row][j] (fp32, stride 66) ----
  {
    float* lg = ARN;
#pragma unroll
    for (int js = 0; js < 4; js++) {
      const float wb2 = w2b[js * 16 + l15];
      const int rbase = w * 16 + quad * 4;
#pragma unroll
      for (int reg = 0; reg < 4; reg++)
        lg[(rbase + reg) * LSd + js * 16 + l15] = acc2[js][reg] + wb2;
    }
  }
  __syncthreads();

  // ---- softmax over the 16 neighbors: one (q, jj) per thread ----
  {
    const int q = t >> 6, jj = t & 63;
    float* base = &ARN[(q * 16) * LSd + jj];
    float v[NSv];
#pragma unroll
    for (int k = 0; k < NSv; k++) v[k] = base[k * LSd];
    float mx = v[0];
#pragma unroll
    for (int k = 1; k < NSv; k++) mx = fmaxf(mx, v[k]);
    float s = 0.0f;
#pragma unroll
    for (int k = 0; k < NSv; k++) { v[k] = __expf(v[k] - mx); s += v[k]; }
    const float is = 1.0f / s;
#pragma unroll
    for (int k = 0; k < NSv; k++) base[k * LSd] = v[k] * is;
  }
  __syncthreads();

  // ---- out[q][c]: H-fold. sum_k sm*pr == pa*H0 + pb*H1 + pc*H2 + pd (sum sm = 1) ----
  {
    const int q = t >> 6, cb = t & 63;
    int mk[NSv];
    float smv[NSv];
    float H0 = 0.f, H1 = 0.f, H2 = 0.f;
    const float* smb = &ARN[(q * 16) * LSd];
#pragma unroll
    for (int k = 0; k < NSv; k++) {
      mk[k] = idx_s[q * 16 + k];
      const float s0 = smb[k * LSd + cb];
      smv[k] = s0;
      H0 = fmaf(h_s[q * 16 + k][0], s0, H0);
      H1 = fmaf(h_s[q * 16 + k][1], s0, H1);
      H2 = fmaf(h_s[q * 16 + k][2], s0, H2);
    }
    float* ob = out + (b * Nv + n0 + q) * Cv;
    const float* xvb = xv + b * Nv * Cv;
#pragma unroll 1
    for (int ii = 0; ii < 8; ii++) {
      const int c = cb + ii * 64;
      float s0 = 0.f, s1 = 0.f, s2 = 0.f, s3 = 0.f;
#pragma unroll
      for (int k = 0; k < NSv; k += 4) {
        s0 = fmaf(xvb[mk[k + 0] * Cv + c], smv[k + 0], s0);
        s1 = fmaf(xvb[mk[k + 1] * Cv + c], smv[k + 1], s1);
        s2 = fmaf(xvb[mk[k + 2] * Cv + c], smv[k + 2], s2);
        s3 = fmaf(xvb[mk[k + 3] * Cv + c], smv[k + 3], s3);
      }
      float r = (s0 + s1) + (s2 + s3);
      r = fmaf(p2W[c], H0, r);
      r = fmaf(p2W[512 + c], H1, r);
      r = fmaf(p2W[1024 + c], H2, r);
      ob[c] = r + p2b[c];
    }
  }
}

extern "C" void kernel_launch(void* const* d_in, const int* in_sizes, int n_in,
                              void* d_out, int out_size, void* d_ws, size_t ws_size,
                              hipStream_t stream) {
  const float* p    = (const float*)d_in[0];
  const float* x    = (const float*)d_in[1];
  const float* Wq   = (const float*)d_in[2];
  const float* bq   = (const float*)d_in[3];
  const float* Wk   = (const float*)d_in[4];
  const float* bk   = (const float*)d_in[5];
  const float* Wv   = (const float*)d_in[6];
  const float* bv   = (const float*)d_in[7];
  const float* p1W  = (const float*)d_in[8];
  const float* p1b  = (const float*)d_in[9];
  const float* pbg  = (const float*)d_in[10];
  const float* pbb  = (const float*)d_in[11];
  const float* p2W  = (const float*)d_in[12];
  const float* p2b  = (const float*)d_in[13];
  const float* bn1g = (const float*)d_in[14];
  const float* bn1b = (const float*)d_in[15];
  const float* w1W  = (const float*)d_in[16];
  const float* w1b  = (const float*)d_in[17];
  const float* bn2g = (const float*)d_in[18];
  const float* bn2b = (const float*)d_in[19];
  const float* w2W  = (const float*)d_in[20];
  const float* w2b  = (const float*)d_in[21];

  // ws layout (bytes): idx int [0, 512 KiB) | xv fp32 16 MiB | xqh/xkh bf16 8 MiB each |
  //   xbT bf16 8 MiB | Wcat bf16 1.5 MiB | w1p 64 KiB | w2p 8 KiB  -> ~42 MiB total
  int*   idxb = (int*)d_ws;
  float* xv   = (float*)((char*)d_ws + 524288);
  u16*   xqh  = (u16*)(xv + 8192 * 512);
  u16*   xkh  = xqh + 8192 * 512;
  u16*   xbT  = xkh + 8192 * 512;
  u16*   Wcat = xbT + 8192 * 512;
  u16*   w1p  = Wcat + 3 * 512 * 512;
  u16*   w2p  = w1p + 64 * 512;

  prep_kernel<<<dim3(1536), 256, 0, stream>>>(p, idxb, x, Wq, Wk, Wv, w1W, w2W,
                                              xbT, Wcat, w1p, w2p);
  qkv_mfma<<<dim3(64, 8), 256, 0, stream>>>(xbT, Wcat, bq, bk, bv, bn1g, bn1b, p2b,
                                            xqh, xkh, xv);
  attn_kernel<<<dim3(2048), 256, 0, stream>>>(p, idxb, xqh, xkh, xv,
                                              p1W, p1b, pbg, pbb, p2W, p2b,
                                              bn1g, bn1b, w1p, w1b, bn2g, bn2b,
                                              w2p, w2b, (float*)d_out);
}